// Round 6
// baseline (213.215 us; speedup 1.0000x reference)
//
#include <hip/hip_runtime.h>

#define T_DIM 2048
#define F_DIM 128
#define B_DIM 16
#define NS 10
#define NTILE 8        // tiles per row: 2048 / (64 lanes * 4 elems)
#define TPB 256        // 4 independent waves per block; wave = one (bf, si)

typedef float floatx4 __attribute__((ext_vector_type(4)));  // native vec for nontemporal store

// Collision-free fast-math wrappers (avoid __exp2f/__log2f glibc macro clash).
__device__ __forceinline__ float fast_exp2(float x) { return __builtin_amdgcn_exp2f(x); }
__device__ __forceinline__ float fast_log2(float x) { return __builtin_amdgcn_logf(x); }
// e^x = 2^(x * log2(e)); args here are small parameter logs, precision ample.
__device__ __forceinline__ float fast_exp(float x) { return fast_exp2(x * 1.44269504088896340736f); }

__global__ __launch_bounds__(TPB, 8) void pcen_kernel(
    const float* __restrict__ x,
    const float* __restrict__ s_log,
    const float* __restrict__ alpha_log,
    const float* __restrict__ delta_log,
    const float* __restrict__ r_log,
    float* __restrict__ out)
{
    const int tid  = threadIdx.x;
    const int lane = tid & 63;
    const int gw   = blockIdx.x * (TPB / 64) + (tid >> 6);  // global wave id
    const int bf   = gw / NS;                               // row (b*F + f)
    const int si   = gw - bf * NS;                          // which s
    const int b    = bf >> 7;                               // bf / F_DIM
    const int f    = bf & (F_DIM - 1);

    const float4* xrow = (const float4*)(x + (size_t)bf * T_DIM);

    // Per-wave scalar parameters.
    const float s  = fast_exp(s_log[si]);
    const float a  = 1.0f - s;
    const float alpha = fast_exp(alpha_log[f]);
    const float delta = fast_exp(delta_log[f]);
    const float r     = fast_exp(r_log[f]);
    const float delta_r   = fast_exp2(r * fast_log2(delta));  // delta^r
    const float neg_alpha = -alpha;

    // Powers of a: pa[bb] = a^(4 * 2^bb), bb = 0..5  (a^4 .. a^128).
    float pa[6];
    {
        float a2 = a * a;
        pa[0] = a2 * a2;
        #pragma unroll
        for (int bb = 1; bb < 6; ++bb) pa[bb] = pa[bb - 1] * pa[bb - 1];
    }
    const float a256 = pa[5] * pa[5];

    // a^(4*lane): product over set bits of lane (no shuffles needed).
    float a4l = 1.0f;
    #pragma unroll
    for (int bb = 0; bb < 6; ++bb) a4l *= ((lane >> bb) & 1) ? pa[bb] : 1.0f;

    // Phase 1: local inclusive scan of each lane's 4 elems (zero carry-in).
    // x consumed immediately -- NOT kept in registers (VGPR slimming).
    float V[NTILE];
    float x0;
    #pragma unroll
    for (int k = 0; k < NTILE; ++k) {
        float4 xk = xrow[k * 64 + lane];
        if (k == 0) x0 = __shfl(xk.x, 0);
        float c = s * xk.x;
        c = fmaf(a, c, s * xk.y);
        c = fmaf(a, c, s * xk.z);
        c = fmaf(a, c, s * xk.w);
        V[k] = c;
    }

    // Phase 2: Kogge-Stone linear scan across lanes. Multiplier per step is
    // the UNIFORM scalar a^(4d), so only v is scanned: one shuffle per step;
    // the 8 tile-scans are independent -> shuffle latency hidden by ILP.
    #pragma unroll
    for (int d = 1, bb = 0; d < 64; d <<= 1, ++bb) {
        #pragma unroll
        for (int k = 0; k < NTILE; ++k) {
            float up = __shfl_up(V[k], d);
            up = (lane >= d) ? up : 0.0f;
            V[k] = fmaf(pa[bb], up, V[k]);
        }
    }

    // Tile-carry chain. Carry-in x0 reproduces y_0 = x_0 exactly as in the
    // reference ((1-s)*x0 + s*x0 = x0).
    float tc = x0;

    float* orow = out + (size_t)(((b * NS + si) * F_DIM) + f) * T_DIM;
    floatx4* orow4 = (floatx4*)orow;

    // Phase 3: re-load x (L1/L2-warm, 8KB/row), recompute each lane's segment
    // with its true carry-in, fuse the PCEN pointwise math; nontemporal
    // coalesced float4 stores (write-once 168MB buffer).
    #pragma unroll
    for (int k = 0; k < NTILE; ++k) {
        float Ve = __shfl_up(V[k], 1);
        Ve = (lane >= 1) ? Ve : 0.0f;
        const float Vl = __shfl(V[k], 63);

        float cc = fmaf(a4l, tc, Ve);      // smoother value just before segment
        const float4 xk = xrow[k * 64 + lane];
        floatx4 o;

        cc = fmaf(a, cc, s * xk.x);
        { float sm2 = fast_exp2(neg_alpha * fast_log2(cc + 1e-5f));
          float base = fmaf(xk.x, sm2, delta);
          o.x = fast_exp2(r * fast_log2(base)) - delta_r; }

        cc = fmaf(a, cc, s * xk.y);
        { float sm2 = fast_exp2(neg_alpha * fast_log2(cc + 1e-5f));
          float base = fmaf(xk.y, sm2, delta);
          o.y = fast_exp2(r * fast_log2(base)) - delta_r; }

        cc = fmaf(a, cc, s * xk.z);
        { float sm2 = fast_exp2(neg_alpha * fast_log2(cc + 1e-5f));
          float base = fmaf(xk.z, sm2, delta);
          o.z = fast_exp2(r * fast_log2(base)) - delta_r; }

        cc = fmaf(a, cc, s * xk.w);
        { float sm2 = fast_exp2(neg_alpha * fast_log2(cc + 1e-5f));
          float base = fmaf(xk.w, sm2, delta);
          o.w = fast_exp2(r * fast_log2(base)) - delta_r; }

        tc = fmaf(a256, tc, Vl);           // carry into next tile

        __builtin_nontemporal_store(o, &orow4[k * 64 + lane]);
    }
}

extern "C" void kernel_launch(void* const* d_in, const int* in_sizes, int n_in,
                              void* d_out, int out_size, void* d_ws, size_t ws_size,
                              hipStream_t stream) {
    const float* x         = (const float*)d_in[0];
    const float* s_log     = (const float*)d_in[1];
    const float* alpha_log = (const float*)d_in[2];
    const float* delta_log = (const float*)d_in[3];
    const float* r_log     = (const float*)d_in[4];
    float* out = (float*)d_out;

    const int total_waves = B_DIM * F_DIM * NS;          // 20480
    const int blocks = total_waves / (TPB / 64);         // 5120

    pcen_kernel<<<dim3(blocks), dim3(TPB), 0, stream>>>(
        x, s_log, alpha_log, delta_log, r_log, out);
}

// Round 7
// 192.735 us; speedup vs baseline: 1.1063x; 1.1063x over previous
//
#include <hip/hip_runtime.h>

#define T_DIM 2048
#define F_DIM 128
#define B_DIM 16
#define NS 10
#define NPAIR 5        // si pairs per row; wave = (bf, pair) -> handles si=2p, 2p+1
#define NTILE 8        // tiles per row: 2048 / (64 lanes * 4 elems)
#define TPB 256        // 4 independent waves per block

typedef float floatx4 __attribute__((ext_vector_type(4)));  // native vec for nontemporal store

// Collision-free fast-math wrappers (avoid __exp2f/__log2f glibc macro clash).
__device__ __forceinline__ float fast_exp2(float x) { return __builtin_amdgcn_exp2f(x); }
__device__ __forceinline__ float fast_log2(float x) { return __builtin_amdgcn_logf(x); }
// e^x = 2^(x * log2(e)); args are small parameter logs, precision ample.
__device__ __forceinline__ float fast_exp(float x) { return fast_exp2(x * 1.44269504088896340736f); }

__global__ __launch_bounds__(TPB) void pcen_kernel(
    const float* __restrict__ x,
    const float* __restrict__ s_log,
    const float* __restrict__ alpha_log,
    const float* __restrict__ delta_log,
    const float* __restrict__ r_log,
    float* __restrict__ out)
{
    const int tid  = threadIdx.x;
    const int lane = tid & 63;
    const int gw   = blockIdx.x * (TPB / 64) + (tid >> 6);  // global wave id
    const int bf   = gw / NPAIR;                            // row (b*F + f)
    const int pr   = gw - bf * NPAIR;                       // si pair index
    const int b    = bf >> 7;                               // bf / F_DIM
    const int f    = bf & (F_DIM - 1);

    const floatx4* xrow = (const floatx4*)(x + (size_t)bf * T_DIM);

    // Load the row ONCE into registers; reused for both si of the pair
    // (both scans and both fused pointwise passes). 32 VGPRs.
    floatx4 xv[NTILE];
    #pragma unroll
    for (int k = 0; k < NTILE; ++k) xv[k] = xrow[k * 64 + lane];
    const float x0 = __shfl(xv[0].x, 0);

    // Per-f parameters (shared across the si pair).
    const float alpha = fast_exp(alpha_log[f]);
    const float delta = fast_exp(delta_log[f]);
    const float r     = fast_exp(r_log[f]);
    const float delta_r   = fast_exp2(r * fast_log2(delta));  // delta^r
    const float neg_alpha = -alpha;

    float* obase = out + (size_t)(((b * NS) * F_DIM) + f) * T_DIM;

    #pragma unroll 1   // keep the two si bodies sharing registers
    for (int p2 = 0; p2 < 2; ++p2) {
        const int si = 2 * pr + p2;
        const float s = fast_exp(s_log[si]);
        const float a = 1.0f - s;

        // Powers of a: pa[bb] = a^(4 * 2^bb), bb = 0..5  (a^4 .. a^128).
        float pa[6];
        {
            float a2 = a * a;
            pa[0] = a2 * a2;
            #pragma unroll
            for (int bb = 1; bb < 6; ++bb) pa[bb] = pa[bb - 1] * pa[bb - 1];
        }
        const float a256 = pa[5] * pa[5];

        // a^(4*lane): product over set bits of lane (no shuffles).
        float a4l = 1.0f;
        #pragma unroll
        for (int bb = 0; bb < 6; ++bb) a4l *= ((lane >> bb) & 1) ? pa[bb] : 1.0f;

        // Phase 1: local inclusive scan of each lane's 4 elems (zero carry-in).
        float V[NTILE];
        #pragma unroll
        for (int k = 0; k < NTILE; ++k) {
            float c = s * xv[k].x;
            c = fmaf(a, c, s * xv[k].y);
            c = fmaf(a, c, s * xv[k].z);
            c = fmaf(a, c, s * xv[k].w);
            V[k] = c;
        }

        // Phase 2: Kogge-Stone linear scan across lanes; uniform multiplier
        // per step (a^(4d)) so only V is shuffled; 8 independent tile-scans
        // hide shuffle latency via ILP.
        #pragma unroll
        for (int d = 1, bb = 0; d < 64; d <<= 1, ++bb) {
            #pragma unroll
            for (int k = 0; k < NTILE; ++k) {
                float up = __shfl_up(V[k], d);
                up = (lane >= d) ? up : 0.0f;
                V[k] = fmaf(pa[bb], up, V[k]);
            }
        }

        // Tile-carry chain; carry-in x0 reproduces y_0 = x_0 exactly.
        float tc = x0;

        floatx4* orow4 = (floatx4*)(obase + (size_t)si * (F_DIM * T_DIM));

        // Phase 3: recompute each lane's segment with true carry-in from
        // register-resident x, fuse PCEN pointwise; nontemporal stores.
        #pragma unroll
        for (int k = 0; k < NTILE; ++k) {
            float Ve = __shfl_up(V[k], 1);
            Ve = (lane >= 1) ? Ve : 0.0f;
            const float Vl = __shfl(V[k], 63);

            float cc = fmaf(a4l, tc, Ve);   // smoother just before segment
            const floatx4 xk = xv[k];
            floatx4 o;

            cc = fmaf(a, cc, s * xk.x);
            { float sm2 = fast_exp2(neg_alpha * fast_log2(cc + 1e-5f));
              float base = fmaf(xk.x, sm2, delta);
              o.x = fast_exp2(r * fast_log2(base)) - delta_r; }

            cc = fmaf(a, cc, s * xk.y);
            { float sm2 = fast_exp2(neg_alpha * fast_log2(cc + 1e-5f));
              float base = fmaf(xk.y, sm2, delta);
              o.y = fast_exp2(r * fast_log2(base)) - delta_r; }

            cc = fmaf(a, cc, s * xk.z);
            { float sm2 = fast_exp2(neg_alpha * fast_log2(cc + 1e-5f));
              float base = fmaf(xk.z, sm2, delta);
              o.z = fast_exp2(r * fast_log2(base)) - delta_r; }

            cc = fmaf(a, cc, s * xk.w);
            { float sm2 = fast_exp2(neg_alpha * fast_log2(cc + 1e-5f));
              float base = fmaf(xk.w, sm2, delta);
              o.w = fast_exp2(r * fast_log2(base)) - delta_r; }

            tc = fmaf(a256, tc, Vl);        // carry into next tile

            __builtin_nontemporal_store(o, &orow4[k * 64 + lane]);
        }
    }
}

extern "C" void kernel_launch(void* const* d_in, const int* in_sizes, int n_in,
                              void* d_out, int out_size, void* d_ws, size_t ws_size,
                              hipStream_t stream) {
    const float* x         = (const float*)d_in[0];
    const float* s_log     = (const float*)d_in[1];
    const float* alpha_log = (const float*)d_in[2];
    const float* delta_log = (const float*)d_in[3];
    const float* r_log     = (const float*)d_in[4];
    float* out = (float*)d_out;

    const int total_waves = B_DIM * F_DIM * NPAIR;       // 10240
    const int blocks = total_waves / (TPB / 64);         // 2560

    pcen_kernel<<<dim3(blocks), dim3(TPB), 0, stream>>>(
        x, s_log, alpha_log, delta_log, r_log, out);
}